// Round 8
// baseline (235.825 us; speedup 1.0000x reference)
//
#include <hip/hip_runtime.h>
#include <hip/hip_bf16.h>

// Inputs fp32, outputs fp32. Internal bf16 MFMA pipeline.
// R14: block-owns-rows flash attention, zero cross-block dependencies.
// Each fattn block owns 32 query rows (half a 64-row tile) and iterates its
// FULL causal range st=0..it: rowsums are block-local (lsum kernel, l
// buffer, atomics all deleted), res stored directly (no memset), attn
// written unnormalized then renormalized in-block (same-XCD L2-hot re-pass,
// unlike R6's cross-XCD finalize), mirrored upper-tile zero folded in.
// Launch graph: 6 nodes -> 3 (wt, qkv, fattn), no memsets, no cooperative
// launch (R13 lesson: coop launch silently no-ops under graph capture).
// Balance: it swizzled so CU's two blocks (bid, bid+256) are complementary
// (it+1)+(32-it)=33 iters. Side effect: fattn ~90us finally tops the
// profile above the 80us fillBuffer curtain -> real counters next round.

typedef __attribute__((ext_vector_type(8))) short bf16x8;
typedef __attribute__((ext_vector_type(4))) float f32x4;

#define NB 8
#define NT 2048
#define NC 1024
#define NH 64

#define VM_DRAIN() asm volatile("s_waitcnt vmcnt(0)" ::: "memory")

__device__ __forceinline__ unsigned short f2bf(float f) {
    unsigned int u = __builtin_bit_cast(unsigned int, f);
    u += 0x7fffu + ((u >> 16) & 1u);   // RNE
    return (unsigned short)(u >> 16);
}

__device__ __forceinline__ bf16x8 cvt8(float4 a, float4 b) {
    union { bf16x8 v; __hip_bfloat162 h[4]; } u;
    u.h[0] = __float22bfloat162_rn(make_float2(a.x, a.y));
    u.h[1] = __float22bfloat162_rn(make_float2(a.z, a.w));
    u.h[2] = __float22bfloat162_rn(make_float2(b.x, b.y));
    u.h[3] = __float22bfloat162_rn(make_float2(b.z, b.w));
    return u.v;
}

// async 16B global->LDS; lds ptr must be wave-uniform (HW adds lane*16).
__device__ __forceinline__ void async_ld16(const void* g, const void* l) {
    __builtin_amdgcn_global_load_lds(
        (const __attribute__((address_space(1))) unsigned int*)g,
        (__attribute__((address_space(3))) unsigned int*)(unsigned int)(unsigned long long)l,
        16, 0, 0);
}

// ---------------------------------------------------------------------------
// Kernel 0: W fp32 [1024][64] -> Wt bf16 [3][64][1024] (transposed), 1/32
// score scale folded into Wq (power of two, lossless).
// ---------------------------------------------------------------------------
__global__ __launch_bounds__(256) void wt_kernel(
        const float* __restrict__ Wq,
        const float* __restrict__ Wk,
        const float* __restrict__ Wv,
        unsigned short* __restrict__ Wt) {
    __shared__ float tile[64][65];
    int m  = blockIdx.x >> 4;
    int k0 = (blockIdx.x & 15) * 64;
    const float* W = (m == 0) ? Wq : ((m == 1) ? Wk : Wv);
    int tid = threadIdx.x;
    for (int i = 0; i < 4; ++i) {
        int f = tid + i * 256;
        int r = f >> 4, c4 = (f & 15) * 4;
        float4 v = *(const float4*)&W[(size_t)(k0 + r) * 64 + c4];
        tile[r][c4 + 0] = v.x; tile[r][c4 + 1] = v.y;
        tile[r][c4 + 2] = v.z; tile[r][c4 + 3] = v.w;
    }
    __syncthreads();
    int n  = tid & 63;
    int kq = (tid >> 6) * 16;
    float scale = (m == 0) ? 0.03125f : 1.0f;
    __attribute__((aligned(16))) unsigned short outv[16];
    for (int j = 0; j < 16; ++j)
        outv[j] = f2bf(tile[kq + j][n] * scale);
    unsigned short* dst = &Wt[(size_t)m * (64 * 1024) + (size_t)n * 1024 + k0 + kq];
    *(uint4*)dst       = *(const uint4*)&outv[0];
    *(uint4*)(dst + 8) = *(const uint4*)&outv[8];
}

// ---------------------------------------------------------------------------
// Kernel 1: qkv GEMM. Grid 512: 32 rows/block, N=192 (q|k|v). Unchanged from
// R11/R12 (passing): A + B double-buffered via global_load_lds (XOR swizzle);
// one barrier per K-step, prefetch pre-compute, explicit vmcnt(0) drain.
// ---------------------------------------------------------------------------
__global__ __launch_bounds__(256) void qkv_kernel(
        const float* __restrict__ x,
        const unsigned short* __restrict__ Wt,
        unsigned short* __restrict__ qkv,
        unsigned short* __restrict__ v_t) {
    __shared__ char smem[65536];

    int tid  = threadIdx.x;
    int wave = tid >> 6, lane = tid & 63, quad = lane >> 4, l15 = lane & 15;
    int row0 = blockIdx.x * 32;

    f32x4 acc[2][3];
#pragma unroll
    for (int rt = 0; rt < 2; ++rt)
#pragma unroll
        for (int j = 0; j < 3; ++j) acc[rt][j] = (f32x4){0.f, 0.f, 0.f, 0.f};

    // prologue: stage kb=0 into buf0
#pragma unroll
    for (int i = 0; i < 2; ++i) {              // A: 32 rows x 256 B
        int s = i * 256 + tid;
        int m = s >> 4, p = s & 15;
        int j = (p & 8) | ((p & 7) ^ (m & 7));
        async_ld16(x + (size_t)(row0 + m) * NC + j * 4,
                   smem + i * 4096 + wave * 1024);
    }
#pragma unroll
    for (int i = 0; i < 6; ++i) {              // B: 192 rows x 128 B
        int s = i * 256 + tid;
        int n = s >> 3, p = s & 7;
        int j = p ^ (n & 7);
        async_ld16(Wt + (size_t)n * NC + j * 8,
                   smem + 8192 + i * 4096 + wave * 1024);
    }

    int cur = 0;
    for (int kb = 0; kb < 16; ++kb) {
        VM_DRAIN();                            // prev prefetch landed in LDS
        __syncthreads();                       // buf[cur] ready for all waves
        if (kb < 15) {                         // prefetch kb+1 -> buf[cur^1]
            char* nb = smem + (cur ^ 1) * 32768;
#pragma unroll
            for (int i = 0; i < 2; ++i) {
                int s = i * 256 + tid;
                int m = s >> 4, p = s & 15;
                int j = (p & 8) | ((p & 7) ^ (m & 7));
                async_ld16(x + (size_t)(row0 + m) * NC + (kb + 1) * 64 + j * 4,
                           nb + i * 4096 + wave * 1024);
            }
#pragma unroll
            for (int i = 0; i < 6; ++i) {
                int s = i * 256 + tid;
                int n = s >> 3, p = s & 7;
                int j = p ^ (n & 7);
                async_ld16(Wt + (size_t)n * NC + (kb + 1) * 64 + j * 8,
                           nb + 8192 + i * 4096 + wave * 1024);
            }
        }
        char* Ab = smem + cur * 32768;
        char* Bb = Ab + 8192;
#pragma unroll
        for (int c = 0; c < 2; ++c) {
            bf16x8 af[2];
#pragma unroll
            for (int rt = 0; rt < 2; ++rt) {
                int m  = rt * 16 + l15;
                int j0 = c * 8 + quad * 2;
                int p0 = (j0 & 8) | ((j0 & 7) ^ (m & 7));
                int p1 = (j0 & 8) | (((j0 + 1) & 7) ^ (m & 7));
                float4 a0 = *(const float4*)(Ab + m * 256 + p0 * 16);
                float4 a1 = *(const float4*)(Ab + m * 256 + p1 * 16);
                af[rt] = cvt8(a0, a1);
            }
#pragma unroll
            for (int jj = 0; jj < 3; ++jj) {
                int n = (wave * 3 + jj) * 16 + l15;
                int p = (c * 4 + quad) ^ (n & 7);
                bf16x8 bf = *(const bf16x8*)(Bb + n * 128 + p * 16);
#pragma unroll
                for (int rt = 0; rt < 2; ++rt)
                    acc[rt][jj] = __builtin_amdgcn_mfma_f32_16x16x32_bf16(
                        af[rt], bf, acc[rt][jj], 0, 0, 0);
            }
        }
        cur ^= 1;
    }

    int b = row0 >> 11;
#pragma unroll
    for (int jj = 0; jj < 3; ++jj) {
        int g   = wave * 3 + jj;
        int mat = g >> 2;
        int col = (g & 3) * 16 + l15;
#pragma unroll
        for (int rt = 0; rt < 2; ++rt) {
            int rowb = row0 + rt * 16 + quad * 4;
            if (mat < 2) {
#pragma unroll
                for (int r = 0; r < 4; ++r)
                    qkv[(size_t)mat * (16384 * 64) + (size_t)(rowb + r) * 64 + col] =
                        f2bf(acc[rt][jj][r]);
            } else {
                union { unsigned long long q; unsigned short us[4]; } pk;
#pragma unroll
                for (int r = 0; r < 4; ++r) pk.us[r] = f2bf(acc[rt][jj][r]);
                *(unsigned long long*)&v_t[((size_t)b * 64 + col) * NT + (rowb & 2047)] = pk.q;
            }
        }
    }
}

// ---------------------------------------------------------------------------
// Kernel 2: fattn. Grid (64, 8). Block owns 32 query rows: gx -> (it, rsp)
// with it = (b&4) ? 31-j : j so CU-paired blocks (bid, bid+256) have
// complementary work (33 iters total). Waves: wr=wave&1 row-half (16 rows),
// wc=wave>>1 col-half (32 cols). Per st tile: QK^T -> e=exp (masked) ->
// ptf LDS -> unnormalized attn store + mirror-zero of upper tile + PV
// accumulate + local rowsum. End: cross-wave rowsum reduce, direct res
// store, in-block attn renormalize (L2-local re-pass).
// ---------------------------------------------------------------------------
__global__ __launch_bounds__(256) void fattn_kernel(
        const unsigned short* __restrict__ qg,
        const unsigned short* __restrict__ kg,
        const unsigned short* __restrict__ vtg,
        float* __restrict__ res,
        float* __restrict__ attn) {
    __shared__ unsigned short kt[2 * 64 * 64];   // K [s][h] swizzled, dbuf
    __shared__ unsigned short vt[2 * 64 * 64];   // V^T [h][s] swizzled, dbuf
    __shared__ float ptf[32 * 68];               // e [row32][s64], pad 4
    __shared__ float rsred[2][32];               // col-half partial rowsums
    __shared__ float rinv_s[32];
    char* ktb = (char*)kt;
    char* vtb = (char*)vt;

    int gx  = blockIdx.x;
    int b   = blockIdx.y;
    int rsp = gx & 1;
    int j   = gx >> 1;
    int it  = (b & 4) ? (31 - j) : j;      // complementary CU pairing
    int tid = threadIdx.x;
    int wave = tid >> 6, lane = tid & 63, quad = lane >> 4, l15 = lane & 15;
    int wr = wave & 1, wc = wave >> 1;
    int tb = it * 64 + rsp * 32;           // block's first query row
    size_t brow = (size_t)b * NT;

    // Q fragments: 16 rows (wr half), k = c*32 + quad*8
    bf16x8 qf[2];
    {
        const unsigned short* qp = qg + (brow + tb + wr * 16 + l15) * NH + quad * 8;
        qf[0] = *(const bf16x8*)qp;
        qf[1] = *(const bf16x8*)(qp + 32);
    }
    int trow[4];
#pragma unroll
    for (int r = 0; r < 4; ++r) trow[r] = tb + wr * 16 + quad * 4 + r;

    float rs[4] = {0.f, 0.f, 0.f, 0.f};
    f32x4 oacc[2];
    oacc[0] = (f32x4){0.f, 0.f, 0.f, 0.f};
    oacc[1] = (f32x4){0.f, 0.f, 0.f, 0.f};

    // prologue: stage st=0 K,V into buf0
#pragma unroll
    for (int i = 0; i < 2; ++i) {
        int s = i * 256 + tid;
        int r = s >> 3, p = s & 7;
        int jj = p ^ (r & 7);
        async_ld16(kg + (brow + r) * NH + jj * 8,
                   ktb + i * 4096 + wave * 1024);
        async_ld16(vtg + ((size_t)b * 64 + r) * NT + jj * 8,
                   vtb + i * 4096 + wave * 1024);
    }

    int cur = 0;
    for (int st = 0; st <= it; ++st) {
        VM_DRAIN();                            // prev prefetch landed in LDS
        __syncthreads();                       // buf[cur] ready; ptf reads done
        if (st + 1 <= it) {                    // prefetch next K,V tiles
#pragma unroll
            for (int i = 0; i < 2; ++i) {
                int s = i * 256 + tid;
                int r = s >> 3, p = s & 7;
                int jj = p ^ (r & 7);
                async_ld16(kg + (brow + (st + 1) * 64 + r) * NH + jj * 8,
                           ktb + (cur ^ 1) * 8192 + i * 4096 + wave * 1024);
                async_ld16(vtg + ((size_t)b * 64 + r) * NT + (st + 1) * 64 + jj * 8,
                           vtb + (cur ^ 1) * 8192 + i * 4096 + wave * 1024);
            }
        }
        char* kb = ktb + cur * 8192;
        char* vb = vtb + cur * 8192;

        // QK^T: wave computes S[16 rows (wr)][32 cols (wc)]
        f32x4 sacc[2];
        sacc[0] = (f32x4){0.f, 0.f, 0.f, 0.f};
        sacc[1] = (f32x4){0.f, 0.f, 0.f, 0.f};
#pragma unroll
        for (int c = 0; c < 2; ++c)
#pragma unroll
            for (int ntl = 0; ntl < 2; ++ntl) {
                int n = wc * 32 + ntl * 16 + l15;
                int p = (c * 4 + quad) ^ (n & 7);
                bf16x8 kf = *(const bf16x8*)(kb + n * 128 + p * 16);
                sacc[ntl] = __builtin_amdgcn_mfma_f32_16x16x32_bf16(
                    qf[c], kf, sacc[ntl], 0, 0, 0);
            }

        bool dia = (st == it);
#pragma unroll
        for (int ntl = 0; ntl < 2; ++ntl) {
            int s_g = st * 64 + wc * 32 + ntl * 16 + l15;
#pragma unroll
            for (int r = 0; r < 4; ++r) {
                float e = __expf(sacc[ntl][r]);
                if (dia && s_g > trow[r]) e = 0.f;
                rs[r] += e;
                ptf[(wr * 16 + quad * 4 + r) * 68 + wc * 32 + ntl * 16 + l15] = e;
            }
        }
        __syncthreads();                       // ptf complete (cross-wave)

        // unnormalized attn store: 32 rows x 256 B
#pragma unroll
        for (int k = 0; k < 2; ++k) {
            int f = k * 256 + tid;
            int row = f >> 4, c4 = (f & 15) * 4;
            *(float4*)&attn[(brow + tb + row) * NT + st * 64 + c4] =
                *(const float4*)&ptf[row * 68 + c4];
        }
        // mirror-zero upper tile (st, it) rows rsp*32..+32
        if (st < it) {
            float4 z4 = {0.f, 0.f, 0.f, 0.f};
#pragma unroll
            for (int k = 0; k < 2; ++k) {
                int f = k * 256 + tid;
                int row = f >> 4, c4 = (f & 15) * 4;
                *(float4*)&attn[(brow + st * 64 + rsp * 32 + row) * NT + it * 64 + c4] = z4;
            }
        }

        // PV (unnormalized): A = P rows (wr half), B = V^T cols (wc half)
#pragma unroll
        for (int c = 0; c < 2; ++c) {
            const float* pp = &ptf[(wr * 16 + l15) * 68 + c * 32 + quad * 8];
            float4 a0 = *(const float4*)pp;
            float4 a1 = *(const float4*)(pp + 4);
            bf16x8 pf = cvt8(a0, a1);
#pragma unroll
            for (int ntl = 0; ntl < 2; ++ntl) {
                int n = wc * 32 + ntl * 16 + l15;
                int p = (c * 4 + quad) ^ (n & 7);
                bf16x8 vf = *(const bf16x8*)(vb + n * 128 + p * 16);
                oacc[ntl] = __builtin_amdgcn_mfma_f32_16x16x32_bf16(
                    pf, vf, oacc[ntl], 0, 0, 0);
            }
        }
        cur ^= 1;
    }

    // block-local rowsum: reduce 16 lanes, then the two col-halves via LDS
#pragma unroll
    for (int r = 0; r < 4; ++r) {
        float v = rs[r];
        v += __shfl_xor(v, 1, 16);
        v += __shfl_xor(v, 2, 16);
        v += __shfl_xor(v, 4, 16);
        v += __shfl_xor(v, 8, 16);
        if (l15 == 0) rsred[wc][wr * 16 + quad * 4 + r] = v;
    }
    __syncthreads();
    if (tid < 32) rinv_s[tid] = 1.0f / (rsred[0][tid] + rsred[1][tid]);
    __syncthreads();

    // res: direct store (no atomics, no memset)
#pragma unroll
    for (int ntl = 0; ntl < 2; ++ntl)
#pragma unroll
        for (int r = 0; r < 4; ++r)
            res[(size_t)(brow + trow[r]) * NH + wc * 32 + ntl * 16 + l15] =
                oacc[ntl][r] * rinv_s[wr * 16 + quad * 4 + r];

    // in-block attn renormalize: re-pass over the block's tiles (L2-local;
    // each thread re-reads exactly the addresses it stored)
    VM_DRAIN();
    for (int st2 = 0; st2 <= it; ++st2) {
#pragma unroll
        for (int k = 0; k < 2; ++k) {
            int f = k * 256 + tid;
            int row = f >> 4, c4 = (f & 15) * 4;
            float* p = &attn[(brow + tb + row) * NT + st2 * 64 + c4];
            float4 v = *(const float4*)p;
            float sc = rinv_s[row];
            v.x *= sc; v.y *= sc; v.z *= sc; v.w *= sc;
            *(float4*)p = v;
        }
    }
}

// ---------------------------------------------------------------------------
extern "C" void kernel_launch(void* const* d_in, const int* in_sizes, int n_in,
                              void* d_out, int out_size, void* d_ws, size_t ws_size,
                              hipStream_t stream) {
    const float* x  = (const float*)d_in[0];
    const float* Wq = (const float*)d_in[1];
    const float* Wk = (const float*)d_in[2];
    const float* Wv = (const float*)d_in[3];

    unsigned short* ws  = (unsigned short*)d_ws;
    unsigned short* Wt  = ws;                          // 3*64*1024 bf16
    unsigned short* qkv = ws + 3 * 64 * 1024;          // 2*16384*64 bf16 (q,k)
    unsigned short* v_t = qkv + 2 * 16384 * 64;        // 16384*64 bf16 [b][h][t]

    float* res  = (float*)d_out;                       // [8,2048,64]
    float* attn = res + (size_t)NB * NT * NH;          // [8,2048,2048]

    hipLaunchKernelGGL(wt_kernel, dim3(48), dim3(256), 0, stream, Wq, Wk, Wv, Wt);
    hipLaunchKernelGGL(qkv_kernel, dim3(512), dim3(256), 0, stream, x, Wt, qkv, v_t);

    const unsigned short* qg = qkv;
    const unsigned short* kg = qkv + 16384 * 64;

    hipLaunchKernelGGL(fattn_kernel, dim3(64, 8), dim3(256), 0, stream,
                       qg, kg, v_t, res, attn);
}

// Round 9
// 220.076 us; speedup vs baseline: 1.0716x; 1.0716x over previous
//
#include <hip/hip_runtime.h>
#include <hip/hip_bf16.h>

// Inputs fp32, outputs fp32. Internal bf16 MFMA pipeline.
// R15: two-pass in-block flash attention. R14 lesson: any second pass over
// attn (renorm re-pass) costs ~27us; R5..R14 lesson: work deltas move dur
// 1:1, scheduling changes move nothing. So: keep R14's dependency-free
// block-owns-rows fattn (no lsum kernel, no l buffer, no atomics, no
// memsets) but get rowsums via an in-block PASS 1 (K-only staging, QK^T,
// exp, accumulate) and store NORMALIZED attn in PASS 2 (no re-pass).
// PV runs on normalized P -> res stored directly (same numerics as R12's
// attn_m: absmax 0.0078). qkv/wt unchanged from R12 (stable, passing).

typedef __attribute__((ext_vector_type(8))) short bf16x8;
typedef __attribute__((ext_vector_type(4))) float f32x4;

#define NB 8
#define NT 2048
#define NC 1024
#define NH 64

#define VM_DRAIN() asm volatile("s_waitcnt vmcnt(0)" ::: "memory")

__device__ __forceinline__ unsigned short f2bf(float f) {
    unsigned int u = __builtin_bit_cast(unsigned int, f);
    u += 0x7fffu + ((u >> 16) & 1u);   // RNE
    return (unsigned short)(u >> 16);
}

__device__ __forceinline__ bf16x8 cvt8(float4 a, float4 b) {
    union { bf16x8 v; __hip_bfloat162 h[4]; } u;
    u.h[0] = __float22bfloat162_rn(make_float2(a.x, a.y));
    u.h[1] = __float22bfloat162_rn(make_float2(a.z, a.w));
    u.h[2] = __float22bfloat162_rn(make_float2(b.x, b.y));
    u.h[3] = __float22bfloat162_rn(make_float2(b.z, b.w));
    return u.v;
}

// async 16B global->LDS; lds ptr must be wave-uniform (HW adds lane*16).
__device__ __forceinline__ void async_ld16(const void* g, const void* l) {
    __builtin_amdgcn_global_load_lds(
        (const __attribute__((address_space(1))) unsigned int*)g,
        (__attribute__((address_space(3))) unsigned int*)(unsigned int)(unsigned long long)l,
        16, 0, 0);
}

// ---------------------------------------------------------------------------
// Kernel 0: W fp32 [1024][64] -> Wt bf16 [3][64][1024] (transposed), 1/32
// score scale folded into Wq (power of two, lossless).
// ---------------------------------------------------------------------------
__global__ __launch_bounds__(256) void wt_kernel(
        const float* __restrict__ Wq,
        const float* __restrict__ Wk,
        const float* __restrict__ Wv,
        unsigned short* __restrict__ Wt) {
    __shared__ float tile[64][65];
    int m  = blockIdx.x >> 4;
    int k0 = (blockIdx.x & 15) * 64;
    const float* W = (m == 0) ? Wq : ((m == 1) ? Wk : Wv);
    int tid = threadIdx.x;
    for (int i = 0; i < 4; ++i) {
        int f = tid + i * 256;
        int r = f >> 4, c4 = (f & 15) * 4;
        float4 v = *(const float4*)&W[(size_t)(k0 + r) * 64 + c4];
        tile[r][c4 + 0] = v.x; tile[r][c4 + 1] = v.y;
        tile[r][c4 + 2] = v.z; tile[r][c4 + 3] = v.w;
    }
    __syncthreads();
    int n  = tid & 63;
    int kq = (tid >> 6) * 16;
    float scale = (m == 0) ? 0.03125f : 1.0f;
    __attribute__((aligned(16))) unsigned short outv[16];
    for (int j = 0; j < 16; ++j)
        outv[j] = f2bf(tile[kq + j][n] * scale);
    unsigned short* dst = &Wt[(size_t)m * (64 * 1024) + (size_t)n * 1024 + k0 + kq];
    *(uint4*)dst       = *(const uint4*)&outv[0];
    *(uint4*)(dst + 8) = *(const uint4*)&outv[8];
}

// ---------------------------------------------------------------------------
// Kernel 1: qkv GEMM. Grid 512: 32 rows/block, N=192 (q|k|v). Unchanged from
// R11/R12 (passing): A + B double-buffered via global_load_lds (XOR swizzle);
// one barrier per K-step, prefetch pre-compute, explicit vmcnt(0) drain.
// ---------------------------------------------------------------------------
__global__ __launch_bounds__(256) void qkv_kernel(
        const float* __restrict__ x,
        const unsigned short* __restrict__ Wt,
        unsigned short* __restrict__ qkv,
        unsigned short* __restrict__ v_t) {
    __shared__ char smem[65536];

    int tid  = threadIdx.x;
    int wave = tid >> 6, lane = tid & 63, quad = lane >> 4, l15 = lane & 15;
    int row0 = blockIdx.x * 32;

    f32x4 acc[2][3];
#pragma unroll
    for (int rt = 0; rt < 2; ++rt)
#pragma unroll
        for (int j = 0; j < 3; ++j) acc[rt][j] = (f32x4){0.f, 0.f, 0.f, 0.f};

    // prologue: stage kb=0 into buf0
#pragma unroll
    for (int i = 0; i < 2; ++i) {              // A: 32 rows x 256 B
        int s = i * 256 + tid;
        int m = s >> 4, p = s & 15;
        int j = (p & 8) | ((p & 7) ^ (m & 7));
        async_ld16(x + (size_t)(row0 + m) * NC + j * 4,
                   smem + i * 4096 + wave * 1024);
    }
#pragma unroll
    for (int i = 0; i < 6; ++i) {              // B: 192 rows x 128 B
        int s = i * 256 + tid;
        int n = s >> 3, p = s & 7;
        int j = p ^ (n & 7);
        async_ld16(Wt + (size_t)n * NC + j * 8,
                   smem + 8192 + i * 4096 + wave * 1024);
    }

    int cur = 0;
    for (int kb = 0; kb < 16; ++kb) {
        VM_DRAIN();                            // prev prefetch landed in LDS
        __syncthreads();                       // buf[cur] ready for all waves
        if (kb < 15) {                         // prefetch kb+1 -> buf[cur^1]
            char* nb = smem + (cur ^ 1) * 32768;
#pragma unroll
            for (int i = 0; i < 2; ++i) {
                int s = i * 256 + tid;
                int m = s >> 4, p = s & 15;
                int j = (p & 8) | ((p & 7) ^ (m & 7));
                async_ld16(x + (size_t)(row0 + m) * NC + (kb + 1) * 64 + j * 4,
                           nb + i * 4096 + wave * 1024);
            }
#pragma unroll
            for (int i = 0; i < 6; ++i) {
                int s = i * 256 + tid;
                int n = s >> 3, p = s & 7;
                int j = p ^ (n & 7);
                async_ld16(Wt + (size_t)n * NC + (kb + 1) * 64 + j * 8,
                           nb + 8192 + i * 4096 + wave * 1024);
            }
        }
        char* Ab = smem + cur * 32768;
        char* Bb = Ab + 8192;
#pragma unroll
        for (int c = 0; c < 2; ++c) {
            bf16x8 af[2];
#pragma unroll
            for (int rt = 0; rt < 2; ++rt) {
                int m  = rt * 16 + l15;
                int j0 = c * 8 + quad * 2;
                int p0 = (j0 & 8) | ((j0 & 7) ^ (m & 7));
                int p1 = (j0 & 8) | (((j0 + 1) & 7) ^ (m & 7));
                float4 a0 = *(const float4*)(Ab + m * 256 + p0 * 16);
                float4 a1 = *(const float4*)(Ab + m * 256 + p1 * 16);
                af[rt] = cvt8(a0, a1);
            }
#pragma unroll
            for (int jj = 0; jj < 3; ++jj) {
                int n = (wave * 3 + jj) * 16 + l15;
                int p = (c * 4 + quad) ^ (n & 7);
                bf16x8 bf = *(const bf16x8*)(Bb + n * 128 + p * 16);
#pragma unroll
                for (int rt = 0; rt < 2; ++rt)
                    acc[rt][jj] = __builtin_amdgcn_mfma_f32_16x16x32_bf16(
                        af[rt], bf, acc[rt][jj], 0, 0, 0);
            }
        }
        cur ^= 1;
    }

    int b = row0 >> 11;
#pragma unroll
    for (int jj = 0; jj < 3; ++jj) {
        int g   = wave * 3 + jj;
        int mat = g >> 2;
        int col = (g & 3) * 16 + l15;
#pragma unroll
        for (int rt = 0; rt < 2; ++rt) {
            int rowb = row0 + rt * 16 + quad * 4;
            if (mat < 2) {
#pragma unroll
                for (int r = 0; r < 4; ++r)
                    qkv[(size_t)mat * (16384 * 64) + (size_t)(rowb + r) * 64 + col] =
                        f2bf(acc[rt][jj][r]);
            } else {
                union { unsigned long long q; unsigned short us[4]; } pk;
#pragma unroll
                for (int r = 0; r < 4; ++r) pk.us[r] = f2bf(acc[rt][jj][r]);
                *(unsigned long long*)&v_t[((size_t)b * 64 + col) * NT + (rowb & 2047)] = pk.q;
            }
        }
    }
}

// ---------------------------------------------------------------------------
// Kernel 2: fattn, two-pass. Grid (64, 8). Block owns 32 query rows
// (it = (b&4)? 31-j : j balance swizzle, rsp = row-half). 4 waves:
// wr=wave&1 row-half (16 rows), wc=wave>>1 col-half (32 cols).
// PASS 1 (K only): QK^T + masked exp -> block-local rowsums -> rinv.
// PASS 2 (K+V): QK^T again, p = exp*rinv (normalized), ptf -> coalesced
// attn stores + mirror-zero upper tile + PV accumulate -> direct res store.
// No atomics, no memsets, no second pass over attn.
// ---------------------------------------------------------------------------
__global__ __launch_bounds__(256) void fattn_kernel(
        const unsigned short* __restrict__ qg,
        const unsigned short* __restrict__ kg,
        const unsigned short* __restrict__ vtg,
        float* __restrict__ res,
        float* __restrict__ attn) {
    __shared__ unsigned short kt[2 * 64 * 64];   // K [s][h] swizzled, dbuf
    __shared__ unsigned short vt[2 * 64 * 64];   // V^T [h][s] swizzled, dbuf
    __shared__ float ptf[32 * 68];               // p [row32][s64], pad 4
    __shared__ float rsred[2][32];               // col-half partial rowsums
    __shared__ float rinv_s[32];
    char* ktb = (char*)kt;
    char* vtb = (char*)vt;

    int gx  = blockIdx.x;
    int b   = blockIdx.y;
    int rsp = gx & 1;
    int j   = gx >> 1;
    int it  = (b & 4) ? (31 - j) : j;      // complementary pairing
    int tid = threadIdx.x;
    int wave = tid >> 6, lane = tid & 63, quad = lane >> 4, l15 = lane & 15;
    int wr = wave & 1, wc = wave >> 1;
    int tb = it * 64 + rsp * 32;           // block's first query row
    size_t brow = (size_t)b * NT;

    // Q fragments: 16 rows (wr half), k = c*32 + quad*8
    bf16x8 qf[2];
    {
        const unsigned short* qp = qg + (brow + tb + wr * 16 + l15) * NH + quad * 8;
        qf[0] = *(const bf16x8*)qp;
        qf[1] = *(const bf16x8*)(qp + 32);
    }
    int trow[4];
#pragma unroll
    for (int r = 0; r < 4; ++r) trow[r] = tb + wr * 16 + quad * 4 + r;

    float rs[4] = {0.f, 0.f, 0.f, 0.f};

    // ================= PASS 1: rowsums (K staging only) =================
#pragma unroll
    for (int i = 0; i < 2; ++i) {
        int s = i * 256 + tid;
        int r = s >> 3, p = s & 7;
        int jj = p ^ (r & 7);
        async_ld16(kg + (brow + r) * NH + jj * 8,
                   ktb + i * 4096 + wave * 1024);
    }
    int cur = 0;
    for (int st = 0; st <= it; ++st) {
        VM_DRAIN();                            // prev prefetch landed
        __syncthreads();                       // buf[cur] ready
        if (st + 1 <= it) {
#pragma unroll
            for (int i = 0; i < 2; ++i) {
                int s = i * 256 + tid;
                int r = s >> 3, p = s & 7;
                int jj = p ^ (r & 7);
                async_ld16(kg + (brow + (st + 1) * 64 + r) * NH + jj * 8,
                           ktb + (cur ^ 1) * 8192 + i * 4096 + wave * 1024);
            }
        }
        char* kb = ktb + cur * 8192;

        f32x4 sacc[2];
        sacc[0] = (f32x4){0.f, 0.f, 0.f, 0.f};
        sacc[1] = (f32x4){0.f, 0.f, 0.f, 0.f};
#pragma unroll
        for (int c = 0; c < 2; ++c)
#pragma unroll
            for (int ntl = 0; ntl < 2; ++ntl) {
                int n = wc * 32 + ntl * 16 + l15;
                int p = (c * 4 + quad) ^ (n & 7);
                bf16x8 kf = *(const bf16x8*)(kb + n * 128 + p * 16);
                sacc[ntl] = __builtin_amdgcn_mfma_f32_16x16x32_bf16(
                    qf[c], kf, sacc[ntl], 0, 0, 0);
            }
        bool dia = (st == it);
#pragma unroll
        for (int ntl = 0; ntl < 2; ++ntl) {
            int s_g = st * 64 + wc * 32 + ntl * 16 + l15;
#pragma unroll
            for (int r = 0; r < 4; ++r) {
                float e = __expf(sacc[ntl][r]);
                if (dia && s_g > trow[r]) e = 0.f;
                rs[r] += e;
            }
        }
        cur ^= 1;
    }

    // block-local rowsum reduce -> rinv
#pragma unroll
    for (int r = 0; r < 4; ++r) {
        float v = rs[r];
        v += __shfl_xor(v, 1, 16);
        v += __shfl_xor(v, 2, 16);
        v += __shfl_xor(v, 4, 16);
        v += __shfl_xor(v, 8, 16);
        if (l15 == 0) rsred[wc][wr * 16 + quad * 4 + r] = v;
    }
    __syncthreads();                           // also: all pass-1 kt reads done
    if (tid < 32) rinv_s[tid] = 1.0f / (rsred[0][tid] + rsred[1][tid]);
    __syncthreads();
    float rinv[4];
#pragma unroll
    for (int r = 0; r < 4; ++r) rinv[r] = rinv_s[wr * 16 + quad * 4 + r];

    // ================= PASS 2: normalized stores + PV ===================
#pragma unroll
    for (int i = 0; i < 2; ++i) {
        int s = i * 256 + tid;
        int r = s >> 3, p = s & 7;
        int jj = p ^ (r & 7);
        async_ld16(kg + (brow + r) * NH + jj * 8,
                   ktb + i * 4096 + wave * 1024);
        async_ld16(vtg + ((size_t)b * 64 + r) * NT + jj * 8,
                   vtb + i * 4096 + wave * 1024);
    }
    cur = 0;
    f32x4 oacc[2];
    oacc[0] = (f32x4){0.f, 0.f, 0.f, 0.f};
    oacc[1] = (f32x4){0.f, 0.f, 0.f, 0.f};

    for (int st = 0; st <= it; ++st) {
        VM_DRAIN();                            // prev prefetch landed
        __syncthreads();                       // buf[cur] ready; ptf reads done
        if (st + 1 <= it) {
#pragma unroll
            for (int i = 0; i < 2; ++i) {
                int s = i * 256 + tid;
                int r = s >> 3, p = s & 7;
                int jj = p ^ (r & 7);
                async_ld16(kg + (brow + (st + 1) * 64 + r) * NH + jj * 8,
                           ktb + (cur ^ 1) * 8192 + i * 4096 + wave * 1024);
                async_ld16(vtg + ((size_t)b * 64 + r) * NT + (st + 1) * 64 + jj * 8,
                           vtb + (cur ^ 1) * 8192 + i * 4096 + wave * 1024);
            }
        }
        char* kb = ktb + cur * 8192;
        char* vb = vtb + cur * 8192;

        f32x4 sacc[2];
        sacc[0] = (f32x4){0.f, 0.f, 0.f, 0.f};
        sacc[1] = (f32x4){0.f, 0.f, 0.f, 0.f};
#pragma unroll
        for (int c = 0; c < 2; ++c)
#pragma unroll
            for (int ntl = 0; ntl < 2; ++ntl) {
                int n = wc * 32 + ntl * 16 + l15;
                int p = (c * 4 + quad) ^ (n & 7);
                bf16x8 kf = *(const bf16x8*)(kb + n * 128 + p * 16);
                sacc[ntl] = __builtin_amdgcn_mfma_f32_16x16x32_bf16(
                    qf[c], kf, sacc[ntl], 0, 0, 0);
            }

        bool dia = (st == it);
#pragma unroll
        for (int ntl = 0; ntl < 2; ++ntl) {
            int s_g = st * 64 + wc * 32 + ntl * 16 + l15;
#pragma unroll
            for (int r = 0; r < 4; ++r) {
                float p = __expf(sacc[ntl][r]) * rinv[r];
                if (dia && s_g > trow[r]) p = 0.f;
                ptf[(wr * 16 + quad * 4 + r) * 68 + wc * 32 + ntl * 16 + l15] = p;
            }
        }
        __syncthreads();                       // ptf complete (cross-wave)

        // normalized attn store: 32 rows x 256 B, coalesced float4
#pragma unroll
        for (int k = 0; k < 2; ++k) {
            int f = k * 256 + tid;
            int row = f >> 4, c4 = (f & 15) * 4;
            *(float4*)&attn[(brow + tb + row) * NT + st * 64 + c4] =
                *(const float4*)&ptf[row * 68 + c4];
        }
        // mirror-zero upper tile (st, it) rows rsp*32..+32
        if (st < it) {
            float4 z4 = {0.f, 0.f, 0.f, 0.f};
#pragma unroll
            for (int k = 0; k < 2; ++k) {
                int f = k * 256 + tid;
                int row = f >> 4, c4 = (f & 15) * 4;
                *(float4*)&attn[(brow + st * 64 + rsp * 32 + row) * NT + it * 64 + c4] = z4;
            }
        }

        // PV (normalized): A = P rows (wr half), B = V^T cols (wc half)
#pragma unroll
        for (int c = 0; c < 2; ++c) {
            const float* pp = &ptf[(wr * 16 + l15) * 68 + c * 32 + quad * 8];
            float4 a0 = *(const float4*)pp;
            float4 a1 = *(const float4*)(pp + 4);
            bf16x8 pf = cvt8(a0, a1);
#pragma unroll
            for (int ntl = 0; ntl < 2; ++ntl) {
                int n = wc * 32 + ntl * 16 + l15;
                int p = (c * 4 + quad) ^ (n & 7);
                bf16x8 vf = *(const bf16x8*)(vb + n * 128 + p * 16);
                oacc[ntl] = __builtin_amdgcn_mfma_f32_16x16x32_bf16(
                    pf, vf, oacc[ntl], 0, 0, 0);
            }
        }
        cur ^= 1;
    }

    // res: direct store (no atomics, no memset)
#pragma unroll
    for (int ntl = 0; ntl < 2; ++ntl)
#pragma unroll
        for (int r = 0; r < 4; ++r)
            res[(size_t)(brow + trow[r]) * NH + wc * 32 + ntl * 16 + l15] = oacc[ntl][r];
}

// ---------------------------------------------------------------------------
extern "C" void kernel_launch(void* const* d_in, const int* in_sizes, int n_in,
                              void* d_out, int out_size, void* d_ws, size_t ws_size,
                              hipStream_t stream) {
    const float* x  = (const float*)d_in[0];
    const float* Wq = (const float*)d_in[1];
    const float* Wk = (const float*)d_in[2];
    const float* Wv = (const float*)d_in[3];

    unsigned short* ws  = (unsigned short*)d_ws;
    unsigned short* Wt  = ws;                          // 3*64*1024 bf16
    unsigned short* qkv = ws + 3 * 64 * 1024;          // 2*16384*64 bf16 (q,k)
    unsigned short* v_t = qkv + 2 * 16384 * 64;        // 16384*64 bf16 [b][h][t]

    float* res  = (float*)d_out;                       // [8,2048,64]
    float* attn = res + (size_t)NB * NT * NH;          // [8,2048,2048]

    hipLaunchKernelGGL(wt_kernel, dim3(48), dim3(256), 0, stream, Wq, Wk, Wv, Wt);
    hipLaunchKernelGGL(qkv_kernel, dim3(512), dim3(256), 0, stream, x, Wt, qkv, v_t);

    const unsigned short* qg = qkv;
    const unsigned short* kg = qkv + 16384 * 64;

    hipLaunchKernelGGL(fattn_kernel, dim3(64, 8), dim3(256), 0, stream,
                       qg, kg, v_t, res, attn);
}